// Round 2
// baseline (718.384 us; speedup 1.0000x reference)
//
#include <hip/hip_runtime.h>

typedef __bf16 bf16;
typedef __bf16 bf16x4 __attribute__((ext_vector_type(4)));
typedef __bf16 bf16x8 __attribute__((ext_vector_type(8)));
typedef float  f32x4  __attribute__((ext_vector_type(4)));

#define BM 256
#define BN 256
#define BK 64

__device__ __forceinline__ void async_copy16(const void* g, void* l) {
    __builtin_amdgcn_global_load_lds(
        (__attribute__((address_space(1))) void*)(g),
        (__attribute__((address_space(3))) void*)(l),
        16, 0, 0);
}

// LDS read: group ((kk*4+q) ^ (row&7)) -> conflict-free b128 (same swizzle as
// the proven 128^2 kernel; SQ_LDS_BANK_CONFLICT measured 0).
#define RD_A(mi, kk) (*(const bf16x8*)&As[par][(wm + (mi)*16 + r) * BK + ((((kk)<<2) + q) ^ sw) * 8])
#define RD_B(ni, kk) (*(const bf16x8*)&Bs[par][(wn + (ni)*16 + r) * BK + ((((kk)<<2) + q) ^ sw) * 8])

// One phase's MFMA cluster: mi-pair {2p,2p+1} x 4 ni x 2 kk = 16 MFMAs (T5 setprio).
#define MM(p) do { \
    __builtin_amdgcn_s_setprio(1); \
    _Pragma("unroll") \
    for (int jj = 0; jj < 2; jj++) { \
        _Pragma("unroll") \
        for (int ni = 0; ni < 4; ni++) { \
            _Pragma("unroll") \
            for (int kk = 0; kk < 2; kk++) \
                acc[2*(p)+jj][ni] = __builtin_amdgcn_mfma_f32_16x16x32_bf16( \
                    av[jj][kk], bv[ni][kk], acc[2*(p)+jj][ni], 0, 0, 0); \
        } \
    } \
    __builtin_amdgcn_s_setprio(0); \
} while (0)

// Phase edges pinned with sched_barrier(0): s_barrier is IntrNoMem in LLVM,
// so without the pins the scheduler may hoist next-phase stage/ds_read ops
// backwards across the closing barrier into the MFMA window (m152-class race;
// same mechanism as rule #18's MFMA hoist, which the post-lgkmcnt pin closes).
#define PHASE_TAIL(p) do { \
    __builtin_amdgcn_sched_barrier(0); \
    __builtin_amdgcn_s_barrier(); \
    asm volatile("s_waitcnt lgkmcnt(0)" ::: "memory"); \
    __builtin_amdgcn_sched_barrier(0); \
    MM(p); \
    __builtin_amdgcn_sched_barrier(0); \
    __builtin_amdgcn_s_barrier(); \
    __builtin_amdgcn_sched_barrier(0); \
} while (0)

// C[z,m,n] = alpha * rs[z,m] * sum_k A[z,m,k]*B[z,n,k]  (+bias[n])
// 256^2 8-phase-style schedule (T3+T4 counted vmcnt, T5 setprio), 512 thr =
// 2x4 waves, per-wave 128x64 out, 128 KiB double-buffered LDS.
// Stage ledger per iter t (half-tile = 128 rows = 2 x global_load_lds_dwordx4):
//   ph0: A0(t+1)->As[par^1]   ph1: A1(t+1)   ph2: B0(t+2)->Bs[par]   ph3: B1(t+2)
//   vmcnt at ph3 pre-barrier: newest load needed by tile t+1 is A1(t+1) (ph1);
//   only B(t+2) (4 loads) issued after it -> s_waitcnt vmcnt(4), never 0 in
//   steady state. WAR safe: B-halves of a buffer are last read in ph0 (bv held
//   in regs), A-halves in ph3; every stage lands >=1 barrier after last read.
__global__ __launch_bounds__(512, 2)
void gemm_nt(const bf16* __restrict__ A, int lda, size_t az,
             const bf16* __restrict__ B, int ldb, size_t bz,
             void* __restrict__ C0, void* __restrict__ C1, void* __restrict__ C2,
             int ldc, size_t cz,
             int M, int N, int K, float alpha,
             const float* __restrict__ bias,
             const float* __restrict__ row_scale, int rsz,
             int out_bf16, int qkv_mode, int causal_skip, int kcap,
             int row_off, int rev_m)
{
    int z  = blockIdx.z;
    int by = rev_m ? (gridDim.y - 1 - blockIdx.y) : blockIdx.y;
    int m0 = by * BM;
    int n0 = blockIdx.x * BN;
    if (causal_skip && n0 > row_off + m0 + BM - 1) return;  // above diagonal
    int Keff = kcap ? min(K, row_off + m0 + BM) : K;        // multiple of 256
    int nk = Keff / BK;
    A += (size_t)z * az;
    B += (size_t)z * bz;

    __shared__ __attribute__((aligned(16))) bf16 As[2][BM * BK];  // 2 x 32 KB
    __shared__ __attribute__((aligned(16))) bf16 Bs[2][BN * BK];  // 2 x 32 KB

    int tid  = threadIdx.x;
    int lane = tid & 63;
    int q    = lane >> 4;     // 0..3  (k-subgroup)
    int r    = lane & 15;     // 0..15 (row-in-16)
    int wave = tid >> 6;      // 0..7
    int wm   = (wave >> 2) * 128;   // wave row block (2)
    int wn   = (wave & 3) * 64;     // wave col block (4)
    int sw   = r & 7;                                 // read-side swizzle
    int gsw  = (((tid & 7) ^ ((tid >> 3) & 7)) * 8);  // stage-side swizzle

    f32x4 acc[8][4];
#pragma unroll
    for (int i = 0; i < 8; i++)
#pragma unroll
        for (int j = 0; j < 4; j++) acc[i][j] = (f32x4){0.f, 0.f, 0.f, 0.f};

    // per-thread staging addresses: 512 thr x 16 B = 8 KB = 64 rows per issue
    const bf16* Ag = A + (size_t)(m0 + (tid >> 3)) * lda + gsw;
    const bf16* Bg = B + (size_t)(n0 + (tid >> 3)) * ldb + gsw;
    char* lA = (char*)&As[0][0] + tid * 16;
    char* lB = (char*)&Bs[0][0] + tid * 16;
    size_t a64 = (size_t)64 * lda;
    size_t b64 = (size_t)64 * ldb;

    // one half-tile (128 rows x BK) = 2 async issues
    auto stA = [&](int kt, int h, int pb) {
        const bf16* g = Ag + (size_t)kt * BK + (h ? 2 * a64 : 0);
        char* l = lA + pb * 32768 + h * 16384;
        async_copy16(g, l);
        async_copy16(g + a64, l + 8192);
    };
    auto stB = [&](int kt, int h, int pb) {
        const bf16* g = Bg + (size_t)kt * BK + (h ? 2 * b64 : 0);
        char* l = lB + pb * 32768 + h * 16384;
        async_copy16(g, l);
        async_copy16(g + b64, l + 8192);
    };

    // prologue: A(0),B(0) -> buf0; B(1) -> buf1.  A(1) staged in iter0 ph0-1.
    stA(0, 0, 0); stA(0, 1, 0);
    stB(0, 0, 0); stB(0, 1, 0);
    if (nk > 1) {
        stB(1, 0, 1); stB(1, 1, 1);
        asm volatile("s_waitcnt vmcnt(4)" ::: "memory");  // tile0 landed, B(1) in flight
    } else {
        asm volatile("s_waitcnt vmcnt(0)" ::: "memory");
    }
    __builtin_amdgcn_sched_barrier(0);
    __builtin_amdgcn_s_barrier();
    __builtin_amdgcn_sched_barrier(0);

    for (int t = 0; t < nk; ++t) {
        int par = t & 1;
        bf16x8 av[2][2], bv[4][2];

        // ---- phase 0: bv (whole tile) + av(mi 0-1); stage A0(t+1) ----
        if (t + 1 < nk) stA(t + 1, 0, par ^ 1);
#pragma unroll
        for (int ni = 0; ni < 4; ni++) { bv[ni][0] = RD_B(ni, 0); bv[ni][1] = RD_B(ni, 1); }
        av[0][0] = RD_A(0, 0); av[0][1] = RD_A(0, 1);
        av[1][0] = RD_A(1, 0); av[1][1] = RD_A(1, 1);
        asm volatile("s_waitcnt lgkmcnt(8)" ::: "memory");  // pace 12-read phase
        PHASE_TAIL(0);

        // ---- phase 1: av(mi 2-3); stage A1(t+1) ----
        if (t + 1 < nk) stA(t + 1, 1, par ^ 1);
        av[0][0] = RD_A(2, 0); av[0][1] = RD_A(2, 1);
        av[1][0] = RD_A(3, 0); av[1][1] = RD_A(3, 1);
        PHASE_TAIL(1);

        // ---- phase 2: av(mi 4-5); stage B0(t+2) ----
        if (t + 2 < nk) stB(t + 2, 0, par);
        av[0][0] = RD_A(4, 0); av[0][1] = RD_A(4, 1);
        av[1][0] = RD_A(5, 0); av[1][1] = RD_A(5, 1);
        PHASE_TAIL(2);

        // ---- phase 3: av(mi 6-7); stage B1(t+2); counted vmcnt for tile t+1 ----
        if (t + 2 < nk) stB(t + 2, 1, par);
        av[0][0] = RD_A(6, 0); av[0][1] = RD_A(6, 1);
        av[1][0] = RD_A(7, 0); av[1][1] = RD_A(7, 1);
        if (t + 1 < nk) {
            if (t + 2 < nk) asm volatile("s_waitcnt vmcnt(4)" ::: "memory");
            else            asm volatile("s_waitcnt vmcnt(0)" ::: "memory");
        }
        PHASE_TAIL(3);
    }

    const float* rs = row_scale ? row_scale + (size_t)z * rsz : nullptr;
    void* Cb = C0;
    if (qkv_mode) { int sel = n0 >> 10; Cb = sel == 0 ? C0 : (sel == 1 ? C1 : C2); }
    // epilogue: C/D layout col=lane&15, row=(lane>>4)*4+j  (m89-verified)
#pragma unroll
    for (int mi = 0; mi < 8; mi++) {
#pragma unroll
        for (int ni = 0; ni < 4; ni++) {
#pragma unroll
            for (int j = 0; j < 4; j++) {
                int row = m0 + wm + mi * 16 + q * 4 + j;
                int col = n0 + wn + ni * 16 + r;
                if (qkv_mode) col &= 1023;
                float v = acc[mi][ni][j] * alpha;
                if (rs)   v *= rs[row];
                if (bias) v += bias[col];
                if (out_bf16) ((bf16*)Cb + (size_t)z * cz)[(size_t)row * ldc + col] = (bf16)v;
                else          ((float*)Cb + (size_t)z * cz)[(size_t)row * ldc + col] = v;
            }
        }
    }
}

// One block per score row, bf16 scores in/out IN PLACE (row stride T bf16).
// Writes unnormalized P zero-padded to the 256-block boundary (PV's Keff cap
// with BM=256 reads exactly up to that boundary) + 1/rowsum.
__global__ __launch_bounds__(256)
void softmax_causal(bf16* __restrict__ S, float* __restrict__ inv_l,
                    int T, int toff, int chunk)
{
    int tr = blockIdx.x, z = blockIdx.y;
    int t  = toff + tr;
    int L  = t + 1;
    int Lw = ((t >> 8) + 1) << 8;   // pad to 256 (matches gemm BM=256 kcap)
    bf16* row = S + ((size_t)z * chunk + tr) * T;
    int tid = threadIdx.x;
    __shared__ float buf[4096];
    __shared__ float red[4];

    for (int s = tid * 8; s < Lw; s += 2048) {
        bf16x8 v = *(const bf16x8*)(row + s);
#pragma unroll
        for (int i = 0; i < 8; i++)
            buf[s + i] = (s + i < L) ? (float)v[i] : -3.0e38f;
    }
    __syncthreads();

    float m = -3.0e38f;
    for (int s = tid; s < Lw; s += 256) m = fmaxf(m, buf[s]);
#pragma unroll
    for (int off = 32; off > 0; off >>= 1) m = fmaxf(m, __shfl_down(m, off, 64));
    if ((tid & 63) == 0) red[tid >> 6] = m;
    __syncthreads();
    m = fmaxf(fmaxf(red[0], red[1]), fmaxf(red[2], red[3]));
    __syncthreads();

    float sum = 0.f;
    for (int s = tid * 8; s < Lw; s += 2048) {
        bf16x8 o;
#pragma unroll
        for (int i = 0; i < 8; i++) {
            float e = __expf(buf[s + i] - m);  // padded lanes -> 0
            sum += e;
            o[i] = (bf16)e;
        }
        *(bf16x8*)(row + s) = o;
    }
#pragma unroll
    for (int off = 32; off > 0; off >>= 1) sum += __shfl_down(sum, off, 64);
    if ((tid & 63) == 0) red[tid >> 6] = sum;
    __syncthreads();
    if (tid == 0) inv_l[(size_t)z * chunk + tr] = 1.0f / (red[0] + red[1] + red[2] + red[3]);
}

// batched transpose: V (B,T,C) -> VT (B,C,T), bf16
__global__ __launch_bounds__(256)
void transpose64(const bf16* __restrict__ V, bf16* __restrict__ VT, int T, int C)
{
    __shared__ bf16 tile[64][65];
    int b  = blockIdx.z;
    int s0 = blockIdx.x * 64, d0 = blockIdx.y * 64;
    const bf16* Vb  = V  + (size_t)b * T * C;
    bf16*       VTb = VT + (size_t)b * T * C;
    int tx = threadIdx.x & 63, ty = threadIdx.x >> 6;
#pragma unroll
    for (int i = 0; i < 64; i += 4)
        tile[ty + i][tx] = Vb[(size_t)(s0 + ty + i) * C + d0 + tx];
    __syncthreads();
#pragma unroll
    for (int i = 0; i < 64; i += 4)
        VTb[(size_t)(d0 + ty + i) * T + s0 + tx] = tile[tx][ty + i];
}

__global__ void cvt_f32_bf16(const float4* __restrict__ in, bf16x4* __restrict__ out, int n4)
{
    int i = blockIdx.x * blockDim.x + threadIdx.x;
    int stride = gridDim.x * blockDim.x;
    for (; i < n4; i += stride) {
        float4 v = in[i];
        bf16x4 o = { (bf16)v.x, (bf16)v.y, (bf16)v.z, (bf16)v.w };
        out[i] = o;
    }
}

extern "C" void kernel_launch(void* const* d_in, const int* in_sizes, int n_in,
                              void* d_out, int out_size, void* d_ws, size_t ws_size,
                              hipStream_t stream)
{
    const int B = 4, T = 4096, C = 1024, M = B * T;
    const float* x  = (const float*)d_in[0];
    const float* Wq = (const float*)d_in[1];
    const float* Wk = (const float*)d_in[2];
    const float* Wv = (const float*)d_in[3];
    const float* Wo = (const float*)d_in[4];
    const float* bo = (const float*)d_in[5];
    float* out = (float*)d_out;

    char* ws = (char*)d_ws;
    size_t off = 0;
    auto alloc = [&](size_t bytes) -> char* {
        char* p = ws + off;
        off += (bytes + 255) & ~(size_t)255;
        return p;
    };
    bf16* Wcat = (bf16*)alloc((size_t)3 * C * C * 2);  // [Wq; Wk; Wv]
    bf16* Wob  = (bf16*)alloc((size_t)C * C * 2);
    bf16* Qb   = (bf16*)alloc((size_t)M * C * 2);
    bf16* Kb   = (bf16*)alloc((size_t)M * C * 2);
    bf16* VT   = (bf16*)alloc((size_t)M * C * 2);

    // Preferred plan (chunk = T, ~232 MB — ws proven >= 235 MB):
    //   S region hosts xb and raw-V during projection (dead before S written);
    //   attention output O aliases Qb (Q dead after the single S-GEMM).
    size_t base = off;
    int chunk = T;
    bf16 *S, *xb, *Vtmp, *Ob;
    float* inv_l;
    {
        size_t need = base + (((size_t)B * T * T * 2 + 255) & ~(size_t)255)
                           + (((size_t)B * T * 4 + 255) & ~(size_t)255);
        if (need <= ws_size) {
            S     = (bf16*)alloc((size_t)B * T * T * 2);
            inv_l = (float*)alloc((size_t)B * T * 4);
            xb    = S;
            Vtmp  = S + (size_t)M * C;   // 32 MB past xb, inside S region
            Ob    = Qb;                  // O overwrites Q after S-GEMM
        } else {
            Ob = (bf16*)alloc((size_t)M * C * 2);
            chunk = T / 2;
            while (chunk > 1024) {
                size_t nd = off + (((size_t)B * chunk * T * 2 + 255) & ~(size_t)255)
                                + (((size_t)B * chunk * 4 + 255) & ~(size_t)255);
                if (nd <= ws_size) break;
                chunk >>= 1;
            }
            S     = (bf16*)alloc((size_t)B * chunk * T * 2);
            inv_l = (float*)alloc((size_t)B * chunk * 4);
            xb    = S;   // x dead after QKV projection
            Vtmp  = Ob;  // V staged in Ob, transposed before PV writes Ob
        }
    }

    dim3 blk(256);
    dim3 gblk(512);

    cvt_f32_bf16<<<dim3(4096), blk, 0, stream>>>((const float4*)x,  (bf16x4*)xb, M * C / 4);
    cvt_f32_bf16<<<dim3(1024), blk, 0, stream>>>((const float4*)Wq, (bf16x4*)(Wcat),             C * C / 4);
    cvt_f32_bf16<<<dim3(1024), blk, 0, stream>>>((const float4*)Wk, (bf16x4*)(Wcat + C * C),     C * C / 4);
    cvt_f32_bf16<<<dim3(1024), blk, 0, stream>>>((const float4*)Wv, (bf16x4*)(Wcat + 2 * C * C), C * C / 4);
    cvt_f32_bf16<<<dim3(1024), blk, 0, stream>>>((const float4*)Wo, (bf16x4*)Wob, C * C / 4);

    // fused QKV projection: [Q|K|V] = X * Wcat^T
    gemm_nt<<<dim3(3 * C / BN, M / BM, 1), gblk, 0, stream>>>(
        xb, C, 0, Wcat, C, 0, Qb, Kb, Vtmp, C, 0, M, 3 * C, C, 1.f,
        nullptr, nullptr, 0, 1, 1, 0, 0, 0, 0);
    transpose64<<<dim3(T / 64, C / 64, B), blk, 0, stream>>>(Vtmp, VT, T, C);

    const float scale = 0.03125f;  // 1/sqrt(1024)
    for (int toff = 0; toff < T; toff += chunk) {
        // S = Q_chunk * K^T * scale  (bf16 out, causal skip, longest-m first)
        gemm_nt<<<dim3(T / BN, chunk / BM, B), gblk, 0, stream>>>(
            Qb + (size_t)toff * C, C, (size_t)T * C,
            Kb, C, (size_t)T * C,
            S, nullptr, nullptr, T, (size_t)chunk * T,
            chunk, T, C, scale,
            nullptr, nullptr, 0, 1, 0, 1, 0, toff, 1);
        // causal softmax in place -> unnormalized bf16 P (256-padded) + 1/rowsum
        softmax_causal<<<dim3(chunk, B), blk, 0, stream>>>(S, inv_l, T, toff, chunk);
        // O = P * V  (NT vs VT, K capped at diagonal, scaled by 1/l, longest first)
        gemm_nt<<<dim3(C / BN, chunk / BM, B), gblk, 0, stream>>>(
            S, T, (size_t)chunk * T,
            VT, T, (size_t)T * C,
            Ob + (size_t)toff * C, nullptr, nullptr, C, (size_t)T * C,
            chunk, C, T, 1.f,
            nullptr, inv_l, chunk, 1, 0, 0, 1, toff, 1);
    }

    // Y = O * Wo^T + bo  (fp32 out)
    gemm_nt<<<dim3(C / BN, M / BM, 1), gblk, 0, stream>>>(
        Ob, C, 0, Wob, C, 0, out, nullptr, nullptr, C, 0, M, C, C, 1.f,
        bo, nullptr, 0, 0, 0, 0, 0, 0, 0);
}

// Round 3
// 718.146 us; speedup vs baseline: 1.0003x; 1.0003x over previous
//
#include <hip/hip_runtime.h>

typedef __bf16 bf16;
typedef __bf16 bf16x4 __attribute__((ext_vector_type(4)));
typedef __bf16 bf16x8 __attribute__((ext_vector_type(8)));
typedef float  f32x4  __attribute__((ext_vector_type(4)));

#define BM 256
#define BN 256
#define BK 64

__device__ __forceinline__ void async_copy16(const void* g, void* l) {
    __builtin_amdgcn_global_load_lds(
        (__attribute__((address_space(1))) void*)(g),
        (__attribute__((address_space(3))) void*)(l),
        16, 0, 0);
}

// LDS read: group ((kk*4+q) ^ (row&7)) -> conflict-free b128 (same swizzle as
// the proven 128^2 kernel; SQ_LDS_BANK_CONFLICT measured 0).
#define RD_A(mi, kk) (*(const bf16x8*)&As[par][(wm + (mi)*16 + r) * BK + ((((kk)<<2) + q) ^ sw) * 8])
#define RD_B(ni, kk) (*(const bf16x8*)&Bs[par][(wn + (ni)*16 + r) * BK + ((((kk)<<2) + q) ^ sw) * 8])

// One phase's MFMA cluster: mi-pair {2p,2p+1} x 4 ni x 2 kk = 16 MFMAs (T5 setprio).
#define MM(p) do { \
    __builtin_amdgcn_s_setprio(1); \
    _Pragma("unroll") \
    for (int jj = 0; jj < 2; jj++) { \
        _Pragma("unroll") \
        for (int ni = 0; ni < 4; ni++) { \
            _Pragma("unroll") \
            for (int kk = 0; kk < 2; kk++) \
                acc[2*(p)+jj][ni] = __builtin_amdgcn_mfma_f32_16x16x32_bf16( \
                    av[jj][kk], bv[ni][kk], acc[2*(p)+jj][ni], 0, 0, 0); \
        } \
    } \
    __builtin_amdgcn_s_setprio(0); \
} while (0)

// m201 template verbatim: NO sched_barrier pins (m141: order-pinning = -42%).
// Safety: ds_reads/MFMA are compiler-visible deps (rule-18 inline-asm hazard
// does not apply); s_barrier is a MI-level scheduling fence for memory ops;
// cross-wave staging correctness rests on counted vmcnt + barriers only.
#define PHASE_TAIL(p) do { \
    __builtin_amdgcn_s_barrier(); \
    asm volatile("s_waitcnt lgkmcnt(0)" ::: "memory"); \
    MM(p); \
    __builtin_amdgcn_s_barrier(); \
} while (0)

// C[z,m,n] = alpha * rs[z,m] * sum_k A[z,m,k]*B[z,n,k]  (+bias[n])
// 256^2 8-phase-style schedule (T3+T4 counted vmcnt, T5 setprio), 512 thr =
// 2x4 waves, per-wave 128x64 out, 128 KiB double-buffered LDS.
// Stage ledger per iter t (half-tile = 128 rows = 2 x global_load_lds_dwordx4):
//   ph0: A0(t+1)->As[par^1]   ph1: A1(t+1)   ph2: B0(t+2)->Bs[par]   ph3: B1(t+2)
//   vmcnt at ph3 pre-barrier: newest load needed by tile t+1 is A1(t+1) (ph1);
//   only B(t+2) (4 loads) issued after it -> s_waitcnt vmcnt(4), never 0 in
//   steady state. WAR safe: B-halves of a buffer are last read in ph0 (bv held
//   in regs), A-halves in ph3; every stage lands >=1 barrier after last read.
__global__ __launch_bounds__(512, 2)
void gemm_nt(const bf16* __restrict__ A, int lda, size_t az,
             const bf16* __restrict__ B, int ldb, size_t bz,
             void* __restrict__ C0, void* __restrict__ C1, void* __restrict__ C2,
             int ldc, size_t cz,
             int M, int N, int K, float alpha,
             const float* __restrict__ bias,
             const float* __restrict__ row_scale, int rsz,
             int out_bf16, int qkv_mode, int causal_skip, int kcap,
             int row_off, int rev_m)
{
    int z  = blockIdx.z;
    int by = rev_m ? (gridDim.y - 1 - blockIdx.y) : blockIdx.y;
    int m0 = by * BM;
    int n0 = blockIdx.x * BN;
    if (causal_skip && n0 > row_off + m0 + BM - 1) return;  // above diagonal
    int Keff = kcap ? min(K, row_off + m0 + BM) : K;        // multiple of 256
    int nk = Keff / BK;
    A += (size_t)z * az;
    B += (size_t)z * bz;

    __shared__ __attribute__((aligned(16))) bf16 As[2][BM * BK];  // 2 x 32 KB
    __shared__ __attribute__((aligned(16))) bf16 Bs[2][BN * BK];  // 2 x 32 KB

    int tid  = threadIdx.x;
    int lane = tid & 63;
    int q    = lane >> 4;     // 0..3  (k-subgroup)
    int r    = lane & 15;     // 0..15 (row-in-16)
    int wave = tid >> 6;      // 0..7
    int wm   = (wave >> 2) * 128;   // wave row block (2)
    int wn   = (wave & 3) * 64;     // wave col block (4)
    int sw   = r & 7;                                 // read-side swizzle
    int gsw  = (((tid & 7) ^ ((tid >> 3) & 7)) * 8);  // stage-side swizzle

    f32x4 acc[8][4];
#pragma unroll
    for (int i = 0; i < 8; i++)
#pragma unroll
        for (int j = 0; j < 4; j++) acc[i][j] = (f32x4){0.f, 0.f, 0.f, 0.f};

    // per-thread staging addresses: 512 thr x 16 B = 8 KB = 64 rows per issue
    const bf16* Ag = A + (size_t)(m0 + (tid >> 3)) * lda + gsw;
    const bf16* Bg = B + (size_t)(n0 + (tid >> 3)) * ldb + gsw;
    char* lA = (char*)&As[0][0] + tid * 16;
    char* lB = (char*)&Bs[0][0] + tid * 16;
    size_t a64 = (size_t)64 * lda;
    size_t b64 = (size_t)64 * ldb;

    // one half-tile (128 rows x BK) = 2 async issues
    auto stA = [&](int kt, int h, int pb) {
        const bf16* g = Ag + (size_t)kt * BK + (h ? 2 * a64 : 0);
        char* l = lA + pb * 32768 + h * 16384;
        async_copy16(g, l);
        async_copy16(g + a64, l + 8192);
    };
    auto stB = [&](int kt, int h, int pb) {
        const bf16* g = Bg + (size_t)kt * BK + (h ? 2 * b64 : 0);
        char* l = lB + pb * 32768 + h * 16384;
        async_copy16(g, l);
        async_copy16(g + b64, l + 8192);
    };

    // prologue: A(0),B(0) -> buf0; B(1) -> buf1.  A(1) staged in iter0 ph0-1.
    stA(0, 0, 0); stA(0, 1, 0);
    stB(0, 0, 0); stB(0, 1, 0);
    if (nk > 1) {
        stB(1, 0, 1); stB(1, 1, 1);
        asm volatile("s_waitcnt vmcnt(4)" ::: "memory");  // tile0 landed, B(1) in flight
    } else {
        asm volatile("s_waitcnt vmcnt(0)" ::: "memory");
    }
    __builtin_amdgcn_s_barrier();

    for (int t = 0; t < nk; ++t) {
        int par = t & 1;
        bf16x8 av[2][2], bv[4][2];

        // ---- phase 0: bv (whole tile) + av(mi 0-1); stage A0(t+1) ----
        if (t + 1 < nk) stA(t + 1, 0, par ^ 1);
#pragma unroll
        for (int ni = 0; ni < 4; ni++) { bv[ni][0] = RD_B(ni, 0); bv[ni][1] = RD_B(ni, 1); }
        av[0][0] = RD_A(0, 0); av[0][1] = RD_A(0, 1);
        av[1][0] = RD_A(1, 0); av[1][1] = RD_A(1, 1);
        asm volatile("s_waitcnt lgkmcnt(8)" ::: "memory");  // pace 12-read phase
        PHASE_TAIL(0);

        // ---- phase 1: av(mi 2-3); stage A1(t+1) ----
        if (t + 1 < nk) stA(t + 1, 1, par ^ 1);
        av[0][0] = RD_A(2, 0); av[0][1] = RD_A(2, 1);
        av[1][0] = RD_A(3, 0); av[1][1] = RD_A(3, 1);
        PHASE_TAIL(1);

        // ---- phase 2: av(mi 4-5); stage B0(t+2) ----
        if (t + 2 < nk) stB(t + 2, 0, par);
        av[0][0] = RD_A(4, 0); av[0][1] = RD_A(4, 1);
        av[1][0] = RD_A(5, 0); av[1][1] = RD_A(5, 1);
        PHASE_TAIL(2);

        // ---- phase 3: av(mi 6-7); stage B1(t+2); counted vmcnt for tile t+1 ----
        if (t + 2 < nk) stB(t + 2, 1, par);
        av[0][0] = RD_A(6, 0); av[0][1] = RD_A(6, 1);
        av[1][0] = RD_A(7, 0); av[1][1] = RD_A(7, 1);
        if (t + 1 < nk) {
            if (t + 2 < nk) asm volatile("s_waitcnt vmcnt(4)" ::: "memory");
            else            asm volatile("s_waitcnt vmcnt(0)" ::: "memory");
        }
        PHASE_TAIL(3);
    }

    const float* rs = row_scale ? row_scale + (size_t)z * rsz : nullptr;
    void* Cb = C0;
    if (qkv_mode) { int sel = n0 >> 10; Cb = sel == 0 ? C0 : (sel == 1 ? C1 : C2); }
    // epilogue: C/D layout col=lane&15, row=(lane>>4)*4+j  (m89-verified)
#pragma unroll
    for (int mi = 0; mi < 8; mi++) {
#pragma unroll
        for (int ni = 0; ni < 4; ni++) {
#pragma unroll
            for (int j = 0; j < 4; j++) {
                int row = m0 + wm + mi * 16 + q * 4 + j;
                int col = n0 + wn + ni * 16 + r;
                if (qkv_mode) col &= 1023;
                float v = acc[mi][ni][j] * alpha;
                if (rs)   v *= rs[row];
                if (bias) v += bias[col];
                if (out_bf16) ((bf16*)Cb + (size_t)z * cz)[(size_t)row * ldc + col] = (bf16)v;
                else          ((float*)Cb + (size_t)z * cz)[(size_t)row * ldc + col] = v;
            }
        }
    }
}

// One block per score row, bf16 scores in/out IN PLACE (row stride T bf16).
// Writes unnormalized P zero-padded to the 256-block boundary (PV's Keff cap
// with BM=256 reads exactly up to that boundary) + 1/rowsum.
__global__ __launch_bounds__(256)
void softmax_causal(bf16* __restrict__ S, float* __restrict__ inv_l,
                    int T, int toff, int chunk)
{
    int tr = blockIdx.x, z = blockIdx.y;
    int t  = toff + tr;
    int L  = t + 1;
    int Lw = ((t >> 8) + 1) << 8;   // pad to 256 (matches gemm BM=256 kcap)
    bf16* row = S + ((size_t)z * chunk + tr) * T;
    int tid = threadIdx.x;
    __shared__ float buf[4096];
    __shared__ float red[4];

    for (int s = tid * 8; s < Lw; s += 2048) {
        bf16x8 v = *(const bf16x8*)(row + s);
#pragma unroll
        for (int i = 0; i < 8; i++)
            buf[s + i] = (s + i < L) ? (float)v[i] : -3.0e38f;
    }
    __syncthreads();

    float m = -3.0e38f;
    for (int s = tid; s < Lw; s += 256) m = fmaxf(m, buf[s]);
#pragma unroll
    for (int off = 32; off > 0; off >>= 1) m = fmaxf(m, __shfl_down(m, off, 64));
    if ((tid & 63) == 0) red[tid >> 6] = m;
    __syncthreads();
    m = fmaxf(fmaxf(red[0], red[1]), fmaxf(red[2], red[3]));
    __syncthreads();

    float sum = 0.f;
    for (int s = tid * 8; s < Lw; s += 2048) {
        bf16x8 o;
#pragma unroll
        for (int i = 0; i < 8; i++) {
            float e = __expf(buf[s + i] - m);  // padded lanes -> 0
            sum += e;
            o[i] = (bf16)e;
        }
        *(bf16x8*)(row + s) = o;
    }
#pragma unroll
    for (int off = 32; off > 0; off >>= 1) sum += __shfl_down(sum, off, 64);
    if ((tid & 63) == 0) red[tid >> 6] = sum;
    __syncthreads();
    if (tid == 0) inv_l[(size_t)z * chunk + tr] = 1.0f / (red[0] + red[1] + red[2] + red[3]);
}

// batched transpose: V (B,T,C) -> VT (B,C,T), bf16
__global__ __launch_bounds__(256)
void transpose64(const bf16* __restrict__ V, bf16* __restrict__ VT, int T, int C)
{
    __shared__ bf16 tile[64][65];
    int b  = blockIdx.z;
    int s0 = blockIdx.x * 64, d0 = blockIdx.y * 64;
    const bf16* Vb  = V  + (size_t)b * T * C;
    bf16*       VTb = VT + (size_t)b * T * C;
    int tx = threadIdx.x & 63, ty = threadIdx.x >> 6;
#pragma unroll
    for (int i = 0; i < 64; i += 4)
        tile[ty + i][tx] = Vb[(size_t)(s0 + ty + i) * C + d0 + tx];
    __syncthreads();
#pragma unroll
    for (int i = 0; i < 64; i += 4)
        VTb[(size_t)(d0 + ty + i) * T + s0 + tx] = tile[tx][ty + i];
}

__global__ void cvt_f32_bf16(const float4* __restrict__ in, bf16x4* __restrict__ out, int n4)
{
    int i = blockIdx.x * blockDim.x + threadIdx.x;
    int stride = gridDim.x * blockDim.x;
    for (; i < n4; i += stride) {
        float4 v = in[i];
        bf16x4 o = { (bf16)v.x, (bf16)v.y, (bf16)v.z, (bf16)v.w };
        out[i] = o;
    }
}

extern "C" void kernel_launch(void* const* d_in, const int* in_sizes, int n_in,
                              void* d_out, int out_size, void* d_ws, size_t ws_size,
                              hipStream_t stream)
{
    const int B = 4, T = 4096, C = 1024, M = B * T;
    const float* x  = (const float*)d_in[0];
    const float* Wq = (const float*)d_in[1];
    const float* Wk = (const float*)d_in[2];
    const float* Wv = (const float*)d_in[3];
    const float* Wo = (const float*)d_in[4];
    const float* bo = (const float*)d_in[5];
    float* out = (float*)d_out;

    char* ws = (char*)d_ws;
    size_t off = 0;
    auto alloc = [&](size_t bytes) -> char* {
        char* p = ws + off;
        off += (bytes + 255) & ~(size_t)255;
        return p;
    };
    bf16* Wcat = (bf16*)alloc((size_t)3 * C * C * 2);  // [Wq; Wk; Wv]
    bf16* Wob  = (bf16*)alloc((size_t)C * C * 2);
    bf16* Qb   = (bf16*)alloc((size_t)M * C * 2);
    bf16* Kb   = (bf16*)alloc((size_t)M * C * 2);
    bf16* VT   = (bf16*)alloc((size_t)M * C * 2);

    // Preferred plan (chunk = T, ~232 MB — ws proven >= 235 MB):
    //   S region hosts xb and raw-V during projection (dead before S written);
    //   attention output O aliases Qb (Q dead after the single S-GEMM).
    size_t base = off;
    int chunk = T;
    bf16 *S, *xb, *Vtmp, *Ob;
    float* inv_l;
    {
        size_t need = base + (((size_t)B * T * T * 2 + 255) & ~(size_t)255)
                           + (((size_t)B * T * 4 + 255) & ~(size_t)255);
        if (need <= ws_size) {
            S     = (bf16*)alloc((size_t)B * T * T * 2);
            inv_l = (float*)alloc((size_t)B * T * 4);
            xb    = S;
            Vtmp  = S + (size_t)M * C;   // 32 MB past xb, inside S region
            Ob    = Qb;                  // O overwrites Q after S-GEMM
        } else {
            Ob = (bf16*)alloc((size_t)M * C * 2);
            chunk = T / 2;
            while (chunk > 1024) {
                size_t nd = off + (((size_t)B * chunk * T * 2 + 255) & ~(size_t)255)
                                + (((size_t)B * chunk * 4 + 255) & ~(size_t)255);
                if (nd <= ws_size) break;
                chunk >>= 1;
            }
            S     = (bf16*)alloc((size_t)B * chunk * T * 2);
            inv_l = (float*)alloc((size_t)B * chunk * 4);
            xb    = S;   // x dead after QKV projection
            Vtmp  = Ob;  // V staged in Ob, transposed before PV writes Ob
        }
    }

    dim3 blk(256);
    dim3 gblk(512);

    cvt_f32_bf16<<<dim3(4096), blk, 0, stream>>>((const float4*)x,  (bf16x4*)xb, M * C / 4);
    cvt_f32_bf16<<<dim3(1024), blk, 0, stream>>>((const float4*)Wq, (bf16x4*)(Wcat),             C * C / 4);
    cvt_f32_bf16<<<dim3(1024), blk, 0, stream>>>((const float4*)Wk, (bf16x4*)(Wcat + C * C),     C * C / 4);
    cvt_f32_bf16<<<dim3(1024), blk, 0, stream>>>((const float4*)Wv, (bf16x4*)(Wcat + 2 * C * C), C * C / 4);
    cvt_f32_bf16<<<dim3(1024), blk, 0, stream>>>((const float4*)Wo, (bf16x4*)Wob, C * C / 4);

    // fused QKV projection: [Q|K|V] = X * Wcat^T
    gemm_nt<<<dim3(3 * C / BN, M / BM, 1), gblk, 0, stream>>>(
        xb, C, 0, Wcat, C, 0, Qb, Kb, Vtmp, C, 0, M, 3 * C, C, 1.f,
        nullptr, nullptr, 0, 1, 1, 0, 0, 0, 0);
    transpose64<<<dim3(T / 64, C / 64, B), blk, 0, stream>>>(Vtmp, VT, T, C);

    const float scale = 0.03125f;  // 1/sqrt(1024)
    for (int toff = 0; toff < T; toff += chunk) {
        // S = Q_chunk * K^T * scale  (bf16 out, causal skip, longest-m first)
        gemm_nt<<<dim3(T / BN, chunk / BM, B), gblk, 0, stream>>>(
            Qb + (size_t)toff * C, C, (size_t)T * C,
            Kb, C, (size_t)T * C,
            S, nullptr, nullptr, T, (size_t)chunk * T,
            chunk, T, C, scale,
            nullptr, nullptr, 0, 1, 0, 1, 0, toff, 1);
        // causal softmax in place -> unnormalized bf16 P (256-padded) + 1/rowsum
        softmax_causal<<<dim3(chunk, B), blk, 0, stream>>>(S, inv_l, T, toff, chunk);
        // O = P * V  (NT vs VT, K capped at diagonal, scaled by 1/l, longest first)
        gemm_nt<<<dim3(C / BN, chunk / BM, B), gblk, 0, stream>>>(
            S, T, (size_t)chunk * T,
            VT, T, (size_t)T * C,
            Ob + (size_t)toff * C, nullptr, nullptr, C, (size_t)T * C,
            chunk, C, T, 1.f,
            nullptr, inv_l, chunk, 1, 0, 0, 1, toff, 1);
    }

    // Y = O * Wo^T + bo  (fp32 out)
    gemm_nt<<<dim3(C / BN, M / BM, 1), gblk, 0, stream>>>(
        Ob, C, 0, Wob, C, 0, out, nullptr, nullptr, C, 0, M, C, C, 1.f,
        bo, nullptr, 0, 0, 0, 0, 0, 0, 0);
}

// Round 4
// 644.626 us; speedup vs baseline: 1.1144x; 1.1141x over previous
//
#include <hip/hip_runtime.h>

typedef __bf16 bf16;
typedef __bf16 bf16x4 __attribute__((ext_vector_type(4)));
typedef __bf16 bf16x8 __attribute__((ext_vector_type(8)));
typedef float  f32x4  __attribute__((ext_vector_type(4)));

#define BM 128
#define BN 128
#define BK 64

__device__ __forceinline__ void async_copy16(const void* g, void* l) {
    __builtin_amdgcn_global_load_lds(
        (__attribute__((address_space(1))) void*)(g),
        (__attribute__((address_space(3))) void*)(l),
        16, 0, 0);
}

// C[z,m,n] = alpha * rs[z,m] * sum_k A[z,m,k]*B[z,n,k]  (+bias[n])
// NT GEMM, z-batched, BK=64. Proven 128^2 2-phase structure (round-0 best:
// 445 TF on S-GEMM; 256^2 8-phase port measured WORSE here — 362 TF, r2/r3).
// LDS rows are 128 B; 16B-group index XORed with row&7 both at stage and
// read time -> uniform 2-way bank access per quarter-wave (free, m136).
// qkv_mode: N spans 3 concatenated 1024-col output buffers C0/C1/C2.
// rev_m: longest-work-first block order for triangular (causal/kcap) grids.
// T1 (this round's delta): within-row XCD chunking — bx' = (bx&7)*(gx/8)+bx/8
// when gx%8==0. Hardware XCD = linear_id%8 = bx%8, so XCD k computes a fixed
// contiguous band of gx/8 n0-columns for every row: its B/K panels stay
// L2-resident all dispatch, and same-row tiles become temporally adjacent
// (A-panel L2 reuse). Pure within-row permutation -> causal balance and
// rev_m ordering unchanged (flat chunked swizzle would imbalance causal rows).
__global__ __launch_bounds__(256)
void gemm_nt(const bf16* __restrict__ A, int lda, size_t az,
             const bf16* __restrict__ B, int ldb, size_t bz,
             void* __restrict__ C0, void* __restrict__ C1, void* __restrict__ C2,
             int ldc, size_t cz,
             int M, int N, int K, float alpha,
             const float* __restrict__ bias,
             const float* __restrict__ row_scale, int rsz,
             int out_bf16, int qkv_mode, int causal_skip, int kcap,
             int row_off, int rev_m)
{
    int z  = blockIdx.z;
    int by = rev_m ? (gridDim.y - 1 - blockIdx.y) : blockIdx.y;
    int m0 = by * BM;
    int gx = (int)gridDim.x;
    int bx = (int)blockIdx.x;
    if ((gx & 7) == 0) bx = ((bx & 7) * (gx >> 3)) + (bx >> 3);  // T1 swizzle
    int n0 = bx * BN;
    if (causal_skip && n0 > row_off + m0 + BM - 1) return;  // above diagonal
    int Keff = kcap ? min(K, row_off + m0 + BM) : K;        // multiple of 128
    A += (size_t)z * az;
    B += (size_t)z * bz;

    __shared__ __attribute__((aligned(16))) bf16 As[BM * BK];  // 16 KB
    __shared__ __attribute__((aligned(16))) bf16 Bs[BN * BK];  // 16 KB

    int tid  = threadIdx.x;
    int lane = tid & 63;
    int q    = lane >> 4;    // 0..3  (k-subgroup)
    int r    = lane & 15;    // 0..15 (row-in-16)
    int wave = tid >> 6;
    int wm   = (wave >> 1) * 64;
    int wn   = (wave & 1) * 64;
    int sw   = r & 7;                                     // read-side swizzle
    int gsw  = (((tid & 7) ^ ((tid >> 3) & 7)) * 8);      // stage-side swizzle

    f32x4 acc[4][4];
#pragma unroll
    for (int i = 0; i < 4; i++)
#pragma unroll
        for (int j = 0; j < 4; j++) acc[i][j] = (f32x4){0.f, 0.f, 0.f, 0.f};

    // staging: 8 issues x 4 KB = 32 KB per k-tile. Thread tid owns LDS bytes
    // tid*16 (+4 KB per issue); fetches swizzled global k-group so LDS group
    // p of row rr holds global group p^(rr&7).
    const bf16* Ag = A + (size_t)(m0 + (tid >> 3)) * lda + gsw;
    const bf16* Bg = B + (size_t)(n0 + (tid >> 3)) * ldb + gsw;
    char* lAs = (char*)As + tid * 16;
    char* lBs = (char*)Bs + tid * 16;
    size_t astep = (size_t)32 * lda;
    size_t bstep = (size_t)32 * ldb;

    for (int k0 = 0; k0 < Keff; k0 += BK) {
#pragma unroll
        for (int i = 0; i < 4; i++) {
            async_copy16(Ag + k0 + i * astep, lAs + i * 4096);
            async_copy16(Bg + k0 + i * bstep, lBs + i * 4096);
        }
        asm volatile("s_waitcnt vmcnt(0)" ::: "memory");
        __syncthreads();

#pragma unroll
        for (int kk = 0; kk < 2; kk++) {
            bf16x8 av[4], bv[4];
#pragma unroll
            for (int mi = 0; mi < 4; mi++)
                av[mi] = *(const bf16x8*)&As[(wm + mi * 16 + r) * BK
                                            + (((kk << 2) + q) ^ sw) * 8];
#pragma unroll
            for (int ni = 0; ni < 4; ni++)
                bv[ni] = *(const bf16x8*)&Bs[(wn + ni * 16 + r) * BK
                                            + (((kk << 2) + q) ^ sw) * 8];
#pragma unroll
            for (int mi = 0; mi < 4; mi++)
#pragma unroll
                for (int ni = 0; ni < 4; ni++)
                    acc[mi][ni] = __builtin_amdgcn_mfma_f32_16x16x32_bf16(
                        av[mi], bv[ni], acc[mi][ni], 0, 0, 0);
        }
        __syncthreads();
    }

    const float* rs = row_scale ? row_scale + (size_t)z * rsz : nullptr;
    void* Cb = C0;
    if (qkv_mode) { int sel = n0 >> 10; Cb = sel == 0 ? C0 : (sel == 1 ? C1 : C2); }
    // epilogue: C/D layout col=lane&15, row=(lane>>4)*4+j  (m89-verified)
#pragma unroll
    for (int mi = 0; mi < 4; mi++) {
#pragma unroll
        for (int ni = 0; ni < 4; ni++) {
#pragma unroll
            for (int j = 0; j < 4; j++) {
                int row = m0 + wm + mi * 16 + q * 4 + j;
                int col = n0 + wn + ni * 16 + r;
                if (qkv_mode) col &= 1023;
                float v = acc[mi][ni][j] * alpha;
                if (rs)   v *= rs[row];
                if (bias) v += bias[col];
                if (out_bf16) ((bf16*)Cb + (size_t)z * cz)[(size_t)row * ldc + col] = (bf16)v;
                else          ((float*)Cb + (size_t)z * cz)[(size_t)row * ldc + col] = v;
            }
        }
    }
}

// One block per score row, bf16 scores in/out IN PLACE (row stride T bf16).
// Writes unnormalized P (zero-padded to the 128-block boundary) + 1/rowsum.
__global__ __launch_bounds__(256)
void softmax_causal(bf16* __restrict__ S, float* __restrict__ inv_l,
                    int T, int toff, int chunk)
{
    int tr = blockIdx.x, z = blockIdx.y;
    int t  = toff + tr;
    int L  = t + 1;
    int Lw = ((t >> 7) + 1) << 7;
    bf16* row = S + ((size_t)z * chunk + tr) * T;
    int tid = threadIdx.x;
    __shared__ float buf[4096];
    __shared__ float red[4];

    for (int s = tid * 8; s < Lw; s += 2048) {
        bf16x8 v = *(const bf16x8*)(row + s);
#pragma unroll
        for (int i = 0; i < 8; i++)
            buf[s + i] = (s + i < L) ? (float)v[i] : -3.0e38f;
    }
    __syncthreads();

    float m = -3.0e38f;
    for (int s = tid; s < Lw; s += 256) m = fmaxf(m, buf[s]);
#pragma unroll
    for (int off = 32; off > 0; off >>= 1) m = fmaxf(m, __shfl_down(m, off, 64));
    if ((tid & 63) == 0) red[tid >> 6] = m;
    __syncthreads();
    m = fmaxf(fmaxf(red[0], red[1]), fmaxf(red[2], red[3]));
    __syncthreads();

    float sum = 0.f;
    for (int s = tid * 8; s < Lw; s += 2048) {
        bf16x8 o;
#pragma unroll
        for (int i = 0; i < 8; i++) {
            float e = __expf(buf[s + i] - m);  // padded lanes -> 0
            sum += e;
            o[i] = (bf16)e;
        }
        *(bf16x8*)(row + s) = o;
    }
#pragma unroll
    for (int off = 32; off > 0; off >>= 1) sum += __shfl_down(sum, off, 64);
    if ((tid & 63) == 0) red[tid >> 6] = sum;
    __syncthreads();
    if (tid == 0) inv_l[(size_t)z * chunk + tr] = 1.0f / (red[0] + red[1] + red[2] + red[3]);
}

// batched transpose: V (B,T,C) -> VT (B,C,T), bf16
__global__ __launch_bounds__(256)
void transpose64(const bf16* __restrict__ V, bf16* __restrict__ VT, int T, int C)
{
    __shared__ bf16 tile[64][65];
    int b  = blockIdx.z;
    int s0 = blockIdx.x * 64, d0 = blockIdx.y * 64;
    const bf16* Vb  = V  + (size_t)b * T * C;
    bf16*       VTb = VT + (size_t)b * T * C;
    int tx = threadIdx.x & 63, ty = threadIdx.x >> 6;
#pragma unroll
    for (int i = 0; i < 64; i += 4)
        tile[ty + i][tx] = Vb[(size_t)(s0 + ty + i) * C + d0 + tx];
    __syncthreads();
#pragma unroll
    for (int i = 0; i < 64; i += 4)
        VTb[(size_t)(d0 + ty + i) * T + s0 + tx] = tile[tx][ty + i];
}

__global__ void cvt_f32_bf16(const float4* __restrict__ in, bf16x4* __restrict__ out, int n4)
{
    int i = blockIdx.x * blockDim.x + threadIdx.x;
    int stride = gridDim.x * blockDim.x;
    for (; i < n4; i += stride) {
        float4 v = in[i];
        bf16x4 o = { (bf16)v.x, (bf16)v.y, (bf16)v.z, (bf16)v.w };
        out[i] = o;
    }
}

extern "C" void kernel_launch(void* const* d_in, const int* in_sizes, int n_in,
                              void* d_out, int out_size, void* d_ws, size_t ws_size,
                              hipStream_t stream)
{
    const int B = 4, T = 4096, C = 1024, M = B * T;
    const float* x  = (const float*)d_in[0];
    const float* Wq = (const float*)d_in[1];
    const float* Wk = (const float*)d_in[2];
    const float* Wv = (const float*)d_in[3];
    const float* Wo = (const float*)d_in[4];
    const float* bo = (const float*)d_in[5];
    float* out = (float*)d_out;

    char* ws = (char*)d_ws;
    size_t off = 0;
    auto alloc = [&](size_t bytes) -> char* {
        char* p = ws + off;
        off += (bytes + 255) & ~(size_t)255;
        return p;
    };
    bf16* Wcat = (bf16*)alloc((size_t)3 * C * C * 2);  // [Wq; Wk; Wv]
    bf16* Wob  = (bf16*)alloc((size_t)C * C * 2);
    bf16* Qb   = (bf16*)alloc((size_t)M * C * 2);
    bf16* Kb   = (bf16*)alloc((size_t)M * C * 2);
    bf16* VT   = (bf16*)alloc((size_t)M * C * 2);

    // Preferred plan (chunk = T, ~232 MB — ws proven >= 235 MB in round 1):
    //   S region hosts xb and raw-V during projection (dead before S written);
    //   attention output O aliases Qb (Q dead after the single S-GEMM).
    size_t base = off;
    int chunk = T;
    bf16 *S, *xb, *Vtmp, *Ob;
    float* inv_l;
    {
        size_t need = base + (((size_t)B * T * T * 2 + 255) & ~(size_t)255)
                           + (((size_t)B * T * 4 + 255) & ~(size_t)255);
        if (need <= ws_size) {
            S     = (bf16*)alloc((size_t)B * T * T * 2);
            inv_l = (float*)alloc((size_t)B * T * 4);
            xb    = S;
            Vtmp  = S + (size_t)M * C;   // 32 MB past xb, inside S region
            Ob    = Qb;                  // O overwrites Q after S-GEMM
        } else {
            Ob = (bf16*)alloc((size_t)M * C * 2);
            chunk = T / 2;
            while (chunk > 1024) {
                size_t nd = off + (((size_t)B * chunk * T * 2 + 255) & ~(size_t)255)
                                + (((size_t)B * chunk * 4 + 255) & ~(size_t)255);
                if (nd <= ws_size) break;
                chunk >>= 1;
            }
            S     = (bf16*)alloc((size_t)B * chunk * T * 2);
            inv_l = (float*)alloc((size_t)B * chunk * 4);
            xb    = S;   // x dead after QKV projection
            Vtmp  = Ob;  // V staged in Ob, transposed before PV writes Ob
        }
    }

    dim3 blk(256);

    cvt_f32_bf16<<<dim3(4096), blk, 0, stream>>>((const float4*)x,  (bf16x4*)xb, M * C / 4);
    cvt_f32_bf16<<<dim3(1024), blk, 0, stream>>>((const float4*)Wq, (bf16x4*)(Wcat),             C * C / 4);
    cvt_f32_bf16<<<dim3(1024), blk, 0, stream>>>((const float4*)Wk, (bf16x4*)(Wcat + C * C),     C * C / 4);
    cvt_f32_bf16<<<dim3(1024), blk, 0, stream>>>((const float4*)Wv, (bf16x4*)(Wcat + 2 * C * C), C * C / 4);
    cvt_f32_bf16<<<dim3(1024), blk, 0, stream>>>((const float4*)Wo, (bf16x4*)Wob, C * C / 4);

    // fused QKV projection: [Q|K|V] = X * Wcat^T
    gemm_nt<<<dim3(3 * C / BN, M / BM, 1), blk, 0, stream>>>(
        xb, C, 0, Wcat, C, 0, Qb, Kb, Vtmp, C, 0, M, 3 * C, C, 1.f,
        nullptr, nullptr, 0, 1, 1, 0, 0, 0, 0);
    transpose64<<<dim3(T / 64, C / 64, B), blk, 0, stream>>>(Vtmp, VT, T, C);

    const float scale = 0.03125f;  // 1/sqrt(1024)
    for (int toff = 0; toff < T; toff += chunk) {
        // S = Q_chunk * K^T * scale  (bf16 out, causal skip, longest-m first)
        gemm_nt<<<dim3(T / BN, chunk / BM, B), blk, 0, stream>>>(
            Qb + (size_t)toff * C, C, (size_t)T * C,
            Kb, C, (size_t)T * C,
            S, nullptr, nullptr, T, (size_t)chunk * T,
            chunk, T, C, scale,
            nullptr, nullptr, 0, 1, 0, 1, 0, toff, 1);
        // causal softmax in place -> unnormalized bf16 P + 1/rowsum
        softmax_causal<<<dim3(chunk, B), blk, 0, stream>>>(S, inv_l, T, toff, chunk);
        // O = P * V  (NT vs VT, K capped at diagonal, scaled by 1/l, longest first)
        gemm_nt<<<dim3(C / BN, chunk / BM, B), blk, 0, stream>>>(
            S, T, (size_t)chunk * T,
            VT, T, (size_t)T * C,
            Ob + (size_t)toff * C, nullptr, nullptr, C, (size_t)T * C,
            chunk, C, T, 1.f,
            nullptr, inv_l, chunk, 1, 0, 0, 1, toff, 1);
    }

    // Y = O * Wo^T + bo  (fp32 out)
    gemm_nt<<<dim3(C / BN, M / BM, 1), blk, 0, stream>>>(
        Ob, C, 0, Wob, C, 0, out, nullptr, nullptr, C, 0, M, C, C, 1.f,
        bo, nullptr, 0, 0, 0, 0, 0, 0, 0);
}